// Round 2
// baseline (767.948 us; speedup 1.0000x reference)
//
#include <hip/hip_runtime.h>
#include <math.h>

// Problem constants
#define NTOK 4096      // B*T
#define DIM  1024
#define NE   8
#define FF   4096

// d_out layout (floats): output | gate_logits | topk_idx | expert_counts
#define OUT_LOGITS 4194304
#define OUT_IDX    4227072
#define OUT_CNT    4235264

typedef unsigned short u16;
typedef __bf16 bf16x8 __attribute__((ext_vector_type(8)));
typedef float  f32x4  __attribute__((ext_vector_type(4)));

__device__ __forceinline__ u16 f2bf(float f) {
  union { float f; unsigned u; } v; v.f = f;
  unsigned r = v.u + 0x7fffu + ((v.u >> 16) & 1u);
  return (u16)(r >> 16);
}

__device__ __forceinline__ void gload_lds16(const u16* g, u16* l) {
  __builtin_amdgcn_global_load_lds(
      (const __attribute__((address_space(1))) void*)(g),
      (__attribute__((address_space(3))) void*)(l), 16, 0, 0);
}

// ---------------- x -> bf16 ----------------
__global__ __launch_bounds__(256) void convert_x_kernel(const float* __restrict__ in,
                                                        u16* __restrict__ out) {
  int i = (blockIdx.x * 256 + threadIdx.x) * 4;
  float4 v = *(const float4*)(in + i);
  unsigned a = (unsigned)f2bf(v.x) | ((unsigned)f2bf(v.y) << 16);
  unsigned b = (unsigned)f2bf(v.z) | ((unsigned)f2bf(v.w) << 16);
  *(uint2*)(out + i) = make_uint2(a, b);
}

// ---------------- transpose + convert: in[R][C] f32 -> out[C][R] bf16, per expert z ----------------
// 32x32 tile; vectorized ushort4 writes (full 64B lines per 8-lane group).
__global__ __launch_bounds__(256) void transpose_cvt_kernel(const float* __restrict__ in,
                                                            u16* __restrict__ out,
                                                            int R, int C) {
  __shared__ float tile[32][33];
  int ez = blockIdx.z;
  in  += (size_t)ez * R * C;
  out += (size_t)ez * R * C;
  int c0 = blockIdx.x * 32, r0 = blockIdx.y * 32;
  int t  = threadIdx.x;
  int tx = t & 31, ty = t >> 5;
  #pragma unroll
  for (int j = ty; j < 32; j += 8)
    tile[j][tx] = in[(size_t)(r0 + j) * C + c0 + tx];
  __syncthreads();
  // write: cc = t>>3 (col of in / row of out), rr0 = (t&7)*4
  int cc = t >> 3, rr0 = (t & 7) * 4;
  ushort4 o;
  o.x = f2bf(tile[rr0 + 0][cc]);
  o.y = f2bf(tile[rr0 + 1][cc]);
  o.z = f2bf(tile[rr0 + 2][cc]);
  o.w = f2bf(tile[rr0 + 3][cc]);
  *(ushort4*)(out + (size_t)(c0 + cc) * R + r0 + rr0) = o;
}

// ---------------- gate: fp32 logits, top-2, softmax, routing ----------------
__global__ __launch_bounds__(256) void gate_kernel(const float* __restrict__ x,
                                                   const float* __restrict__ gw,
                                                   const float* __restrict__ gb,
                                                   float* __restrict__ out,
                                                   int* __restrict__ counts,
                                                   int* __restrict__ tok_list,
                                                   float* __restrict__ wt_list) {
  int wave = threadIdx.x >> 6, lane = threadIdx.x & 63;
  int token = blockIdx.x * 4 + wave;
  const float* xr = x + (size_t)token * DIM + lane * 16;
  float acc[NE];
  #pragma unroll
  for (int e = 0; e < NE; e++) acc[e] = 0.f;
  #pragma unroll
  for (int c = 0; c < 16; c += 4) {
    float4 xv = *(const float4*)(xr + c);
    const float* gwr = gw + (size_t)(lane * 16 + c) * NE;
    float xs[4] = {xv.x, xv.y, xv.z, xv.w};
    #pragma unroll
    for (int q = 0; q < 4; q++)
      #pragma unroll
      for (int e = 0; e < NE; e++)
        acc[e] += xs[q] * gwr[q * NE + e];
  }
  #pragma unroll
  for (int off = 32; off; off >>= 1)
    #pragma unroll
    for (int e = 0; e < NE; e++)
      acc[e] += __shfl_down(acc[e], off);

  if (lane == 0) {
    float lg[NE];
    #pragma unroll
    for (int e = 0; e < NE; e++) {
      lg[e] = acc[e] + gb[e];
      out[OUT_LOGITS + token * NE + e] = lg[e];
    }
    int i0 = 0; float v0 = lg[0];
    #pragma unroll
    for (int e = 1; e < NE; e++) if (lg[e] > v0) { v0 = lg[e]; i0 = e; }
    int i1 = -1; float v1 = -1e30f;
    #pragma unroll
    for (int e = 0; e < NE; e++) if (e != i0 && lg[e] > v1) { v1 = lg[e]; i1 = e; }
    float ex = expf(v1 - v0);
    float s = 1.f + ex;
    float w0 = 1.f / s, w1 = ex / s;
    out[OUT_IDX + token * 2]     = (float)i0;
    out[OUT_IDX + token * 2 + 1] = (float)i1;
    int s0 = atomicAdd(&counts[i0], 1);
    tok_list[i0 * NTOK + s0] = token; wt_list[i0 * NTOK + s0] = w0;
    int s1 = atomicAdd(&counts[i1], 1);
    tok_list[i1 * NTOK + s1] = token; wt_list[i1 * NTOK + s1] = w1;
  }
}

// ---------------- scan: offsets + float counts output ----------------
__global__ void scan_kernel(const int* __restrict__ counts, int* __restrict__ offsets,
                            float* __restrict__ cnt_out) {
  if (threadIdx.x == 0) {
    int off = 0;
    for (int e = 0; e < NE; e++) { offsets[e] = off; off += counts[e]; }
  }
  if (threadIdx.x < NE) cnt_out[threadIdx.x] = (float)counts[threadIdx.x];
}

// ---------------- MoE GEMM: MODE 0 = x->h (gelu), MODE 1 = h->out (scaled atomic, split-K=2) ----------------
// LDS bank-conflict fix: k-chunk XOR swizzle by (row>>1)&3, applied on the GLOBAL
// source side (global_load_lds LDS dst is hardware-fixed lane-contiguous).
template <int MODE>
__global__ __launch_bounds__(256) void moe_gemm_kernel(
    const u16* __restrict__ Abase, const u16* __restrict__ Bbase,
    const float* __restrict__ bias,
    const int* __restrict__ counts, const int* __restrict__ offsets,
    const int* __restrict__ tok_list, const float* __restrict__ wt_list,
    u16* __restrict__ Hout, float* __restrict__ Out) {
  constexpr int KT = (MODE == 0) ? DIM : FF;   // reduction length
  constexpr int NT = (MODE == 0) ? FF : DIM;   // output width
  const int e  = blockIdx.z;
  const int ne = counts[e];
  const int m0 = blockIdx.y * 128;
  if (m0 >= ne) return;
  int n0, kbeg, kend;
  if (MODE == 0) {
    n0 = blockIdx.x * 128; kbeg = 0; kend = KT;
  } else {
    n0 = (blockIdx.x & 7) * 128;
    int kc = blockIdx.x >> 3;
    kbeg = kc * (KT / 2); kend = kbeg + KT / 2;
  }
  const int offs = offsets[e];

  __shared__ u16 As[128 * 32];  // [m][k], k-chunk swizzled by (m>>1)&3
  __shared__ u16 Bs[128 * 32];  // [n][k], same swizzle

  const int t = threadIdx.x;
  const int wave = t >> 6, lane = t & 63;
  const int quad = lane >> 4, l16 = lane & 15;
  const int wm = (wave & 1) * 64, wn = (wave >> 1) * 64;

  // staging: thread t covers row (t>>2) [+64], LDS chunk (t&3) fixed by lane;
  // load the swizzled global chunk so LDS[r][c] = global chunk c^((r>>1)&3)
  const int colA = ((t & 3) ^ ((t >> 3) & 3)) * 8;
  const u16* aptr[2];
  const u16* bptr[2];
  #pragma unroll
  for (int p = 0; p < 2; p++) {
    int s  = m0 + p * 64 + (t >> 2);
    int sr = s < ne ? s : ne - 1;
    size_t arow;
    if (MODE == 0) arow = (size_t)tok_list[e * NTOK + sr] * (size_t)KT;
    else           arow = (size_t)(offs + sr) * (size_t)KT;
    aptr[p] = Abase + arow + colA;
    bptr[p] = Bbase + (size_t)e * NT * KT + (size_t)(n0 + p * 64 + (t >> 2)) * KT + colA;
  }
  u16* asDst[2] = { &As[t * 8], &As[2048 + t * 8] };
  u16* bsDst[2] = { &Bs[t * 8], &Bs[2048 + t * 8] };

  // fragment-read swizzle: global chunk q lives at LDS col q^((row>>1)&3)
  const int swz = (l16 >> 1) & 3;

  f32x4 acc[4][4];
  #pragma unroll
  for (int i = 0; i < 4; i++)
    #pragma unroll
    for (int j = 0; j < 4; j++)
      acc[i][j] = (f32x4){0.f, 0.f, 0.f, 0.f};

  for (int k0 = kbeg; k0 < kend; k0 += 32) {
    gload_lds16(aptr[0] + k0, asDst[0]);
    gload_lds16(aptr[1] + k0, asDst[1]);
    gload_lds16(bptr[0] + k0, bsDst[0]);
    gload_lds16(bptr[1] + k0, bsDst[1]);
    __syncthreads();
    bf16x8 af[4], bfr[4];
    const int cread = (quad ^ swz) * 8;
    #pragma unroll
    for (int i = 0; i < 4; i++) {
      af[i]  = *(const bf16x8*)&As[(wm + i * 16 + l16) * 32 + cread];
      bfr[i] = *(const bf16x8*)&Bs[(wn + i * 16 + l16) * 32 + cread];
    }
    #pragma unroll
    for (int i = 0; i < 4; i++)
      #pragma unroll
      for (int j = 0; j < 4; j++)
        acc[i][j] = __builtin_amdgcn_mfma_f32_16x16x32_bf16(af[i], bfr[j], acc[i][j], 0, 0, 0);
    __syncthreads();
  }

  if (MODE == 0) {
    const float* bb = bias + (size_t)e * FF + n0;
    #pragma unroll
    for (int i = 0; i < 4; i++) {
      #pragma unroll
      for (int r = 0; r < 4; r++) {
        int s = m0 + wm + i * 16 + quad * 4 + r;
        if (s < ne) {
          u16* hr = Hout + (size_t)(offs + s) * FF + n0;
          #pragma unroll
          for (int j = 0; j < 4; j++) {
            int nl = wn + j * 16 + l16;
            float v = acc[i][j][r] + bb[nl];
            v = 0.5f * v * (1.f + erff(v * 0.70710678118654752f));
            hr[nl] = f2bf(v);
          }
        }
      }
    }
  } else {
    const bool addb = (kbeg == 0);
    const float* bb = bias + (size_t)e * DIM + n0;
    #pragma unroll
    for (int i = 0; i < 4; i++) {
      #pragma unroll
      for (int r = 0; r < 4; r++) {
        int s = m0 + wm + i * 16 + quad * 4 + r;
        if (s < ne) {
          int   tok = tok_list[e * NTOK + s];
          float w   = wt_list[e * NTOK + s];
          float* orow = Out + (size_t)tok * DIM + n0;
          #pragma unroll
          for (int j = 0; j < 4; j++) {
            int nl = wn + j * 16 + l16;
            float v = (acc[i][j][r] + (addb ? bb[nl] : 0.f)) * w;
            atomicAdd(&orow[nl], v);
          }
        }
      }
    }
  }
}

extern "C" void kernel_launch(void* const* d_in, const int* in_sizes, int n_in,
                              void* d_out, int out_size, void* d_ws, size_t ws_size,
                              hipStream_t stream) {
  const float* x   = (const float*)d_in[0];
  const float* gw  = (const float*)d_in[1];
  const float* gb  = (const float*)d_in[2];
  const float* w1  = (const float*)d_in[3];
  const float* b1  = (const float*)d_in[4];
  const float* w2  = (const float*)d_in[5];
  const float* b2  = (const float*)d_in[6];
  float* out = (float*)d_out;
  char*  ws  = (char*)d_ws;

  // ws layout
  u16* x_bf  = (u16*)(ws);                                  // 8 MB
  u16* w1t   = (u16*)(ws + 8388608);                        // 64 MB  [E][FF][DIM]
  u16* w2t   = (u16*)(ws + 8388608 + 67108864);             // 64 MB  [E][DIM][FF]
  u16* h     = (u16*)(ws + 8388608 + 2ull * 67108864);      // 64 MB  [8192][FF]
  char* meta = ws + 8388608 + 3ull * 67108864;
  int*   counts   = (int*)(meta);
  int*   offsets  = (int*)(meta + 32);
  int*   tok_list = (int*)(meta + 64);
  float* wt_list  = (float*)(meta + 64 + NE * NTOK * 4);
  (void)in_sizes; (void)n_in; (void)out_size; (void)ws_size;

  hipMemsetAsync(out, 0, (size_t)OUT_LOGITS * 4, stream);   // zero main output (atomics accumulate)
  hipMemsetAsync(counts, 0, 32, stream);

  convert_x_kernel<<<NTOK * DIM / (256 * 4), 256, 0, stream>>>(x, x_bf);
  transpose_cvt_kernel<<<dim3(FF / 32, DIM / 32, NE), 256, 0, stream>>>(w1, w1t, DIM, FF);
  transpose_cvt_kernel<<<dim3(DIM / 32, FF / 32, NE), 256, 0, stream>>>(w2, w2t, FF, DIM);
  gate_kernel<<<NTOK / 4, 256, 0, stream>>>(x, gw, gb, out, counts, tok_list, wt_list);
  scan_kernel<<<1, 64, 0, stream>>>(counts, offsets, out + OUT_CNT);
  moe_gemm_kernel<0><<<dim3(FF / 128, NTOK / 128, NE), 256, 0, stream>>>(
      x_bf, w1t, b1, counts, offsets, tok_list, wt_list, h, nullptr);
  moe_gemm_kernel<1><<<dim3(2 * DIM / 128, NTOK / 128, NE), 256, 0, stream>>>(
      h, w2t, b2, counts, offsets, tok_list, wt_list, nullptr, out);
}

// Round 3
// 661.359 us; speedup vs baseline: 1.1612x; 1.1612x over previous
//
#include <hip/hip_runtime.h>
#include <math.h>

// Problem constants
#define NTOK 4096      // B*T
#define DIM  1024
#define NE   8
#define FF   4096

// d_out layout (floats): output | gate_logits | topk_idx | expert_counts
#define OUT_LOGITS 4194304
#define OUT_IDX    4227072
#define OUT_CNT    4235264

typedef unsigned short u16;
typedef __bf16 bf16x8 __attribute__((ext_vector_type(8)));
typedef float  f32x4  __attribute__((ext_vector_type(4)));

__device__ __forceinline__ u16 f2bf(float f) {
  union { float f; unsigned u; } v; v.f = f;
  unsigned r = v.u + 0x7fffu + ((v.u >> 16) & 1u);
  return (u16)(r >> 16);
}

__device__ __forceinline__ float gelu_f(float v) {
  // tanh-approx gelu; |err| vs exact < ~3e-3 absolute, well under 2% threshold
  float u = v * (0.7978845608f + 0.0356774081f * v * v);
  float e = __expf(2.f * u);
  float t = 1.f - 2.f / (e + 1.f);
  return 0.5f * v * (1.f + t);
}

__device__ __forceinline__ void gload_lds16(const u16* g, u16* l) {
  __builtin_amdgcn_global_load_lds(
      (const __attribute__((address_space(1))) void*)(g),
      (__attribute__((address_space(3))) void*)(l), 16, 0, 0);
}

// ---------------- transpose + convert: in[R][C] f32 -> out[C][R] bf16, per expert z ----------------
// 64x64 tile, 256 threads: float4 global reads, b128 LDS writes, ushort4 global writes.
__global__ __launch_bounds__(256) void transpose_cvt_kernel(const float* __restrict__ in,
                                                            u16* __restrict__ out,
                                                            int R, int C) {
  __shared__ float tile[64][68];   // stride 68: 16B-aligned rows, 2-way-max read banks
  in  += (size_t)blockIdx.z * R * C;
  out += (size_t)blockIdx.z * R * C;
  int c0 = blockIdx.x * 64, r0 = blockIdx.y * 64;
  int t = threadIdx.x;
  int cr = (t & 15) * 4, rr = t >> 4;
  #pragma unroll
  for (int p = 0; p < 4; p++) {
    float4 v = *(const float4*)(in + (size_t)(r0 + rr + p * 16) * C + c0 + cr);
    *(float4*)&tile[rr + p * 16][cr] = v;
  }
  __syncthreads();
  int c = t >> 2, rb = (t & 3) * 4;
  u16* orow = out + (size_t)(c0 + c) * R + r0;
  #pragma unroll
  for (int it = 0; it < 4; it++) {
    int r = it * 16 + rb;
    ushort4 o;
    o.x = f2bf(tile[r + 0][c]);
    o.y = f2bf(tile[r + 1][c]);
    o.z = f2bf(tile[r + 2][c]);
    o.w = f2bf(tile[r + 3][c]);
    *(ushort4*)(orow + r) = o;
  }
}

// ---------------- gate: fp32 logits, top-2, softmax; NO atomics ----------------
__global__ __launch_bounds__(256) void gate_kernel(const float* __restrict__ x,
                                                   const float* __restrict__ gw,
                                                   const float* __restrict__ gb,
                                                   float* __restrict__ out,
                                                   int2* __restrict__ tk_idx,
                                                   float2* __restrict__ tk_w) {
  int wave = threadIdx.x >> 6, lane = threadIdx.x & 63;
  int token = blockIdx.x * 4 + wave;
  const float* xr = x + (size_t)token * DIM + lane * 16;
  float acc[NE];
  #pragma unroll
  for (int e = 0; e < NE; e++) acc[e] = 0.f;
  #pragma unroll
  for (int c = 0; c < 16; c += 4) {
    float4 xv = *(const float4*)(xr + c);
    const float* gwr = gw + (size_t)(lane * 16 + c) * NE;
    float xs[4] = {xv.x, xv.y, xv.z, xv.w};
    #pragma unroll
    for (int q = 0; q < 4; q++)
      #pragma unroll
      for (int e = 0; e < NE; e++)
        acc[e] += xs[q] * gwr[q * NE + e];
  }
  #pragma unroll
  for (int off = 32; off; off >>= 1)
    #pragma unroll
    for (int e = 0; e < NE; e++)
      acc[e] += __shfl_down(acc[e], off);

  if (lane == 0) {
    float lg[NE];
    #pragma unroll
    for (int e = 0; e < NE; e++) {
      lg[e] = acc[e] + gb[e];
      out[OUT_LOGITS + token * NE + e] = lg[e];
    }
    int i0 = 0; float v0 = lg[0];
    #pragma unroll
    for (int e = 1; e < NE; e++) if (lg[e] > v0) { v0 = lg[e]; i0 = e; }
    int i1 = -1; float v1 = -1e30f;
    #pragma unroll
    for (int e = 0; e < NE; e++) if (e != i0 && lg[e] > v1) { v1 = lg[e]; i1 = e; }
    float ex = expf(v1 - v0);
    float s = 1.f + ex;
    out[OUT_IDX + token * 2]     = (float)i0;
    out[OUT_IDX + token * 2 + 1] = (float)i1;
    tk_idx[token] = make_int2(i0, i1);
    tk_w[token]   = make_float2(1.f / s, ex / s);
  }
}

// ---------------- build flat routing lists: 1 block, wave e compacts expert e ----------------
__global__ __launch_bounds__(512) void build_lists_kernel(
    const int2* __restrict__ tk_idx, const float2* __restrict__ tk_w,
    int* __restrict__ counts, int* __restrict__ offsets,
    int* __restrict__ tok_list, float* __restrict__ wt_list,
    float* __restrict__ cnt_out) {
  __shared__ int s_cnt[NE];
  int e = threadIdx.x >> 6, lane = threadIdx.x & 63;
  // phase 1: count
  int cnt = 0;
  for (int base = 0; base < NTOK; base += 64) {
    int2 idx = tk_idx[base + lane];
    cnt += __popcll(__ballot(idx.x == e || idx.y == e));
  }
  if (lane == 0) s_cnt[e] = cnt;
  __syncthreads();
  int off = 0;
  for (int ee = 0; ee < e; ee++) off += s_cnt[ee];
  if (lane == 0) {
    counts[e]  = s_cnt[e];
    offsets[e] = off;
    cnt_out[e] = (float)s_cnt[e];
  }
  // phase 2: emit (deterministic, ordered by token)
  int pos = off;
  for (int base = 0; base < NTOK; base += 64) {
    int tok = base + lane;
    int2 idx = tk_idx[tok];
    float2 w = tk_w[tok];
    bool m0 = (idx.x == e), m1 = (idx.y == e);
    bool m = m0 || m1;
    unsigned long long mask = __ballot(m);
    if (m) {
      int p = pos + __popcll(mask & ((1ull << lane) - 1ull));
      tok_list[p] = tok;
      wt_list[p]  = m0 ? w.x : w.y;
    }
    pos += __popcll(mask);
  }
}

// ---------------- gather + convert: xg[slot][:] = bf16(x[tok_list[slot]][:]) ----------------
__global__ __launch_bounds__(256) void gather_x_kernel(const float* __restrict__ x,
                                                       const int* __restrict__ tok_list,
                                                       u16* __restrict__ xg) {
  int g = blockIdx.x;
  int tok = tok_list[g];
  int c = threadIdx.x * 4;
  float4 v = *(const float4*)(x + (size_t)tok * DIM + c);
  ushort4 o;
  o.x = f2bf(v.x); o.y = f2bf(v.y); o.z = f2bf(v.z); o.w = f2bf(v.w);
  *(ushort4*)(xg + (size_t)g * DIM + c) = o;
}

// ---------------- MoE GEMM: MODE 0 = xg->h (gelu), MODE 1 = h->out (scaled atomic) ----------------
template <int MODE>
__global__ __launch_bounds__(256) void moe_gemm_kernel(
    const u16* __restrict__ Abase, const u16* __restrict__ Bbase,
    const float* __restrict__ bias,
    const int* __restrict__ counts, const int* __restrict__ offsets,
    const int* __restrict__ tok_list, const float* __restrict__ wt_list,
    u16* __restrict__ Hout, float* __restrict__ Out) {
  constexpr int KT = (MODE == 0) ? DIM : FF;   // reduction length
  constexpr int NT = (MODE == 0) ? FF : DIM;   // output width
  const int e  = blockIdx.z;
  const int ne = counts[e];
  const int m0 = blockIdx.y * 128;
  if (m0 >= ne) return;
  const int n0   = blockIdx.x * 128;
  const int offs = offsets[e];

  __shared__ u16 As[128 * 32];  // [m][k]
  __shared__ u16 Bs[128 * 32];  // [n][k]

  const int t = threadIdx.x;
  const int wave = t >> 6, lane = t & 63;
  const int quad = lane >> 4, l16 = lane & 15;
  const int wm = (wave & 1) * 64, wn = (wave >> 1) * 64;

  // staging: thread t stages row t>>2 (+64), chunk t&3 — lane-sequential addresses
  const int colA = (t & 3) * 8;
  const u16* aptr[2];
  const u16* bptr[2];
  #pragma unroll
  for (int p = 0; p < 2; p++) {
    int s  = m0 + p * 64 + (t >> 2);
    int sr = s < ne ? s : ne - 1;
    aptr[p] = Abase + (size_t)(offs + sr) * KT + colA;
    bptr[p] = Bbase + (size_t)e * NT * KT + (size_t)(n0 + p * 64 + (t >> 2)) * KT + colA;
  }
  u16* asDst[2] = { &As[t * 8], &As[2048 + t * 8] };
  u16* bsDst[2] = { &Bs[t * 8], &Bs[2048 + t * 8] };

  f32x4 acc[4][4];
  #pragma unroll
  for (int i = 0; i < 4; i++)
    #pragma unroll
    for (int j = 0; j < 4; j++)
      acc[i][j] = (f32x4){0.f, 0.f, 0.f, 0.f};

  for (int k0 = 0; k0 < KT; k0 += 32) {
    gload_lds16(aptr[0] + k0, asDst[0]);
    gload_lds16(aptr[1] + k0, asDst[1]);
    gload_lds16(bptr[0] + k0, bsDst[0]);
    gload_lds16(bptr[1] + k0, bsDst[1]);
    __syncthreads();
    bf16x8 af[4], bfr[4];
    #pragma unroll
    for (int i = 0; i < 4; i++) {
      af[i]  = *(const bf16x8*)&As[(wm + i * 16 + l16) * 32 + quad * 8];
      bfr[i] = *(const bf16x8*)&Bs[(wn + i * 16 + l16) * 32 + quad * 8];
    }
    #pragma unroll
    for (int i = 0; i < 4; i++)
      #pragma unroll
      for (int j = 0; j < 4; j++)
        acc[i][j] = __builtin_amdgcn_mfma_f32_16x16x32_bf16(af[i], bfr[j], acc[i][j], 0, 0, 0);
    __syncthreads();
  }

  if (MODE == 0) {
    const float* bb = bias + (size_t)e * FF + n0;
    #pragma unroll
    for (int i = 0; i < 4; i++) {
      #pragma unroll
      for (int r = 0; r < 4; r++) {
        int s = m0 + wm + i * 16 + quad * 4 + r;
        if (s < ne) {
          u16* hr = Hout + (size_t)(offs + s) * FF + n0;
          #pragma unroll
          for (int j = 0; j < 4; j++) {
            int nl = wn + j * 16 + l16;
            hr[nl] = f2bf(gelu_f(acc[i][j][r] + bb[nl]));
          }
        }
      }
    }
  } else {
    const float* bb = bias + (size_t)e * DIM + n0;
    #pragma unroll
    for (int i = 0; i < 4; i++) {
      #pragma unroll
      for (int r = 0; r < 4; r++) {
        int s = m0 + wm + i * 16 + quad * 4 + r;
        if (s < ne) {
          int   tok = tok_list[offs + s];
          float w   = wt_list[offs + s];
          float* orow = Out + (size_t)tok * DIM + n0;
          #pragma unroll
          for (int j = 0; j < 4; j++) {
            int nl = wn + j * 16 + l16;
            atomicAdd(&orow[nl], (acc[i][j][r] + bb[nl]) * w);
          }
        }
      }
    }
  }
}

extern "C" void kernel_launch(void* const* d_in, const int* in_sizes, int n_in,
                              void* d_out, int out_size, void* d_ws, size_t ws_size,
                              hipStream_t stream) {
  const float* x   = (const float*)d_in[0];
  const float* gw  = (const float*)d_in[1];
  const float* gb  = (const float*)d_in[2];
  const float* w1  = (const float*)d_in[3];
  const float* b1  = (const float*)d_in[4];
  const float* w2  = (const float*)d_in[5];
  const float* b2  = (const float*)d_in[6];
  float* out = (float*)d_out;
  char*  ws  = (char*)d_ws;

  // ws layout
  u16* w1t = (u16*)(ws);                                    // 64 MB  [E][FF][DIM]
  u16* w2t = (u16*)(ws + 1ull * 67108864);                  // 64 MB  [E][DIM][FF]
  u16* h   = (u16*)(ws + 2ull * 67108864);                  // 64 MB  [8192][FF]
  u16* xg  = (u16*)(ws + 3ull * 67108864);                  // 16 MB  [8192][DIM]
  char* meta = ws + 3ull * 67108864 + 16777216;
  int*    counts   = (int*)(meta);
  int*    offsets  = (int*)(meta + 64);
  int*    tok_list = (int*)(meta + 128);                    // flat [8192]
  float*  wt_list  = (float*)(meta + 128 + 32768);          // flat [8192]
  int2*   tk_idx   = (int2*)(meta + 128 + 2 * 32768);       // [4096]
  float2* tk_w     = (float2*)(meta + 128 + 2 * 32768 + 32768);
  (void)in_sizes; (void)n_in; (void)out_size; (void)ws_size;

  hipMemsetAsync(out, 0, (size_t)OUT_LOGITS * 4, stream);   // zero main output (atomics accumulate)

  transpose_cvt_kernel<<<dim3(FF / 64, DIM / 64, NE), 256, 0, stream>>>(w1, w1t, DIM, FF);
  transpose_cvt_kernel<<<dim3(DIM / 64, FF / 64, NE), 256, 0, stream>>>(w2, w2t, FF, DIM);
  gate_kernel<<<NTOK / 4, 256, 0, stream>>>(x, gw, gb, out, tk_idx, tk_w);
  build_lists_kernel<<<1, 512, 0, stream>>>(tk_idx, tk_w, counts, offsets, tok_list, wt_list,
                                            out + OUT_CNT);
  gather_x_kernel<<<2 * NTOK, 256, 0, stream>>>(x, tok_list, xg);
  moe_gemm_kernel<0><<<dim3(FF / 128, NTOK / 128, NE), 256, 0, stream>>>(
      xg, w1t, b1, counts, offsets, tok_list, wt_list, h, nullptr);
  moe_gemm_kernel<1><<<dim3(DIM / 128, NTOK / 128, NE), 256, 0, stream>>>(
      h, w2t, b2, counts, offsets, tok_list, wt_list, nullptr, out);
}